// Round 12
// baseline (2797.582 us; speedup 1.0000x reference)
//
#include <hip/hip_runtime.h>
#include <hip/hip_bf16.h>

// TreeLSTM forward, round 12: round-11 + fused flash-style attention
// (scores+softmax+PV in one kernel; SC fp32 matrix never materialized).
// Topology: 16 perfect ternary trees, depth 6; off[l] l=0..5: {5808,5760,5616,5184,3888,0}.

namespace {

constexpr int NN = 5824;
constexpr int ED = 352;

typedef __bf16 bf16;
typedef short s16x8 __attribute__((ext_vector_type(8)));
typedef float f32x4 __attribute__((ext_vector_type(4)));

__device__ __forceinline__ float sigmoidf_(float x) { return 1.f / (1.f + expf(-x)); }

__device__ __forceinline__ void gload_lds16(const void* g, void* s) {
  __builtin_amdgcn_global_load_lds(
      (const __attribute__((address_space(1))) unsigned int*)g,
      (__attribute__((address_space(3))) unsigned int*)s, 16, 0, 0);
}

// ---------------- bf16 MFMA GEMM ----------------
// C = alpha * (A_hi [+ A_lo]) @ (B_hi [+ B_lo])^T + bias [+Cacc] [relu]
// MFMA stream order fixed: A_hi*B_hi [+ A_hi*B_lo if BPAIR] [+ A_lo*B_hi if DUAL].
// PIPE: 2-phase double-buffered K-loop.
// MODE 0: f32 out (+bias)   MODE 4: pair+relu+bias
// MODE 5: f32+bias+accum    MODE 6: decoder region-select
// MODE 7: bf16+bias+VT scatter (incl. K-pad zero fill)
template <int MODE, bool DUAL, bool BPAIR, bool BF32, bool PIPE>
__global__ __launch_bounds__(256) void bgemm_k(
    const bf16* __restrict__ A, const bf16* __restrict__ Alo,
    const bf16* __restrict__ Bh_, const bf16* __restrict__ Bl_,
    const float* __restrict__ Bf0, const float* __restrict__ Bf1,
    const float* __restrict__ Bf2,
    void* __restrict__ Cp, bf16* __restrict__ Clo, const float* __restrict__ Cacc,
    const float* __restrict__ bias, const float* __restrict__ bias1,
    const float* __restrict__ bias2, bf16* __restrict__ VTout, int mpad,
    int M, int N, int K, int lda, int ldb, int ldc, float alpha,
    long long sA1, long long sA2, long long sB1, long long sB2,
    long long sC1, long long sC2, int nh) {
  const int bz = blockIdx.z;
  const int b1 = bz / nh, b2 = bz - b1 * nh;
  A += (long long)b1 * sA1 + (long long)b2 * sA2;
  if (DUAL) Alo += (long long)b1 * sA1 + (long long)b2 * sA2;
  if (!BF32) {
    Bh_ += (long long)b1 * sB1 + (long long)b2 * sB2;
    if (BPAIR) Bl_ += (long long)b1 * sB1 + (long long)b2 * sB2;
  }
  const long long coff = (long long)b1 * sC1 + (long long)b2 * sC2;
  const int bm = blockIdx.y * 128, bn = blockIdx.x * 128;

  constexpr int NSTG = PIPE ? 2 : 1;
  __shared__ bf16 As[NSTG][128 * 32];
  __shared__ bf16 Ls[DUAL ? NSTG : 1][DUAL ? 128 * 32 : 8];
  __shared__ bf16 Bh[NSTG][128 * 32];
  __shared__ bf16 Bl[BPAIR ? NSTG : 1][BPAIR ? 128 * 32 : 8];
  const int tid = threadIdx.x;
  const int l = tid & 63;
  const int wr = ((tid >> 7) & 1) * 64;
  const int wc = ((tid >> 6) & 1) * 64;
  f32x4 acc[4][4];
#pragma unroll
  for (int i = 0; i < 4; ++i)
#pragma unroll
    for (int j = 0; j < 4; ++j) acc[i][j] = (f32x4){0.f, 0.f, 0.f, 0.f};

  auto STAGE = [&](int st, int k0) {
#pragma unroll
    for (int r = 0; r < 2; ++r) {
      int idx = r * 256 + tid;
      int row = idx >> 2, cs = idx & 3;
      int cg = cs ^ (row & 3);
      int ra = bm + row; if (ra > M - 1) ra = M - 1;
      int rb = bn + row; if (rb > N - 1) rb = N - 1;
      gload_lds16(A + (long long)ra * lda + k0 + cg * 8, &As[st][idx * 8]);
      if (DUAL) gload_lds16(Alo + (long long)ra * lda + k0 + cg * 8, &Ls[st][idx * 8]);
      if (BF32) {
        const float* src;
        if (rb < 5000)      src = Bf0 + (long long)rb * ldb + k0 + cg * 8;
        else if (rb < 5300) src = Bf1 + (long long)(rb - 5000) * ldb + k0 + cg * 8;
        else                src = Bf2 + (long long)(rb - 5300) * ldb + k0 + cg * 8;
        float4 x = *reinterpret_cast<const float4*>(src);
        float4 y = *reinterpret_cast<const float4*>(src + 4);
        float w[8] = {x.x, x.y, x.z, x.w, y.x, y.y, y.z, y.w};
        bf16 hb_[8], lb_[8];
#pragma unroll
        for (int q = 0; q < 8; ++q) {
          bf16 hq = (bf16)w[q];
          hb_[q] = hq;
          lb_[q] = (bf16)(w[q] - (float)hq);
        }
        *reinterpret_cast<s16x8*>(&Bh[st][idx * 8]) = *reinterpret_cast<s16x8*>(hb_);
        if (BPAIR)
          *reinterpret_cast<s16x8*>(&Bl[st][idx * 8]) = *reinterpret_cast<s16x8*>(lb_);
      } else {
        gload_lds16(Bh_ + (long long)rb * ldb + k0 + cg * 8, &Bh[st][idx * 8]);
        if (BPAIR) gload_lds16(Bl_ + (long long)rb * ldb + k0 + cg * 8, &Bl[st][idx * 8]);
      }
    }
  };

  auto COMPUTE = [&](int st) {
    s16x8 af[4], al[4], bh4[4], bl4[4];
#pragma unroll
    for (int mi = 0; mi < 4; ++mi) {
      int row = wr + mi * 16 + (l & 15);
      int ch = ((l >> 4) ^ row) & 3;
      af[mi] = *reinterpret_cast<const s16x8*>(&As[st][row * 32 + ch * 8]);
      if (DUAL) al[mi] = *reinterpret_cast<const s16x8*>(&Ls[st][row * 32 + ch * 8]);
    }
#pragma unroll
    for (int ni = 0; ni < 4; ++ni) {
      int row = wc + ni * 16 + (l & 15);
      int ch = ((l >> 4) ^ row) & 3;
      bh4[ni] = *reinterpret_cast<const s16x8*>(&Bh[st][row * 32 + ch * 8]);
      if (BPAIR) bl4[ni] = *reinterpret_cast<const s16x8*>(&Bl[st][row * 32 + ch * 8]);
    }
#pragma unroll
    for (int mi = 0; mi < 4; ++mi)
#pragma unroll
      for (int ni = 0; ni < 4; ++ni) {
        acc[mi][ni] =
            __builtin_amdgcn_mfma_f32_16x16x32_bf16(af[mi], bh4[ni], acc[mi][ni], 0, 0, 0);
        if (BPAIR)
          acc[mi][ni] =
              __builtin_amdgcn_mfma_f32_16x16x32_bf16(af[mi], bl4[ni], acc[mi][ni], 0, 0, 0);
        if (DUAL)
          acc[mi][ni] =
              __builtin_amdgcn_mfma_f32_16x16x32_bf16(al[mi], bh4[ni], acc[mi][ni], 0, 0, 0);
      }
  };

  if (!PIPE) {
    for (int k0 = 0; k0 < K; k0 += 32) {
      STAGE(0, k0);
      __syncthreads();
      COMPUTE(0);
      __syncthreads();
    }
  } else {
    STAGE(0, 0);
    asm volatile("s_waitcnt vmcnt(0)" ::: "memory");
    __builtin_amdgcn_s_barrier();
    int cur = 0;
    for (int k0 = 0; k0 < K; k0 += 32) {
      if (k0 + 32 < K) STAGE(cur ^ 1, k0 + 32);
      COMPUTE(cur);
      asm volatile("s_waitcnt vmcnt(0)" ::: "memory");
      __builtin_amdgcn_sched_barrier(0);
      __builtin_amdgcn_s_barrier();
      cur ^= 1;
    }
  }

  const int lc = l & 15, lr4 = (l >> 4) * 4;
#pragma unroll
  for (int mi = 0; mi < 4; ++mi) {
#pragma unroll
    for (int j = 0; j < 4; ++j) {
      int r = bm + wr + mi * 16 + lr4 + j;
      if (MODE != 7 && r >= M) continue;
#pragma unroll
      for (int ni = 0; ni < 4; ++ni) {
        int c = bn + wc + ni * 16 + lc;
        if (c >= N) continue;
        float v = alpha * acc[mi][ni][j];
        if (MODE == 6) {
          v += (c < 5000) ? bias[c] : (c < 5300) ? bias1[c - 5000] : bias2[c - 5300];
        } else if (bias) {
          v += bias[c];
        }
        long long idx = coff + (long long)r * ldc + c;
        if (MODE == 7) {
          if (c >= 1024 && r < 3 * mpad) {
            bf16 pv = (r < M) ? (bf16)v : (bf16)0.f;
            int r3 = r % 3, s = r / 3;
            int hh = (c - 1024) >> 8, n = (c - 1024) & 255;
            VTout[(long long)((r3 * 2 + hh) * 256 + n) * mpad + s] = pv;
          }
          if (r < M) ((bf16*)Cp)[idx] = (bf16)v;
        } else if (MODE == 5) {
          ((float*)Cp)[idx] = v + Cacc[idx];
        } else if (MODE == 0) {
          ((float*)Cp)[idx] = v;
        } else if (MODE == 4) {
          v = fmaxf(v, 0.f);
          bf16 hv = (bf16)v;
          ((bf16*)Cp)[idx] = hv;
          Clo[idx] = (bf16)(v - (float)hv);
        } else {  // MODE 6
          float* o0 = (float*)Cp;
          if (c < 5000)      o0[(long long)r * 5000 + c] = v;
          else if (c < 5300) o0[29120000LL + (long long)r * 300 + (c - 5000)] = v;
          else               o0[30867200LL + (long long)r * 1024 + (c - 5300)] = v;
        }
      }
    }
  }
}

static void bgemm(hipStream_t st, int mode, bool dual, bool bpair,
                  const bf16* A, const bf16* Alo, const bf16* Bh, const bf16* Bl,
                  void* Cp, bf16* Clo, const float* Cacc,
                  const float* bias, const float* bias1, const float* bias2,
                  bf16* VTout, int mpad,
                  int M, int N, int K, int lda, int ldb, int ldc, float alpha,
                  int batches = 1, long long sA1 = 0, long long sA2 = 0,
                  long long sB1 = 0, long long sB2 = 0, long long sC1 = 0,
                  long long sC2 = 0, int nh = 1,
                  const float* Bf0 = nullptr, const float* Bf1 = nullptr,
                  const float* Bf2 = nullptr, bool bf32 = false) {
  dim3 g((N + 127) / 128, (M + 127) / 128, batches), b(256);
  long long nblocks = (long long)g.x * g.y * g.z;
  const bool pipe = (!bf32) && (mode != 6) && nblocks <= 1024;
#define BGL(MD_, DU_, BP_, BFF_, PP_)                                                    \
  bgemm_k<MD_, DU_, BP_, BFF_, PP_><<<g, b, 0, st>>>(                                    \
      A, Alo, Bh, Bl, Bf0, Bf1, Bf2, Cp, Clo, Cacc, bias, bias1, bias2, VTout, mpad,     \
      M, N, K, lda, ldb, ldc, alpha, sA1, sA2, sB1, sB2, sC1, sC2, nh)
#define BGL2(MD_, DU_, BP_)                                                              \
  do { if (pipe) BGL(MD_, DU_, BP_, false, true); else BGL(MD_, DU_, BP_, false, false); \
  } while (0)
  if (mode == 0 && !dual && bpair)        BGL2(0, false, true);
  else if (mode == 0 && dual && bpair)    BGL2(0, true, true);
  else if (mode == 4)                     BGL2(4, true, true);
  else if (mode == 5)                     BGL2(5, true, true);
  else if (mode == 6 && !bf32)            BGL(6, false, false, false, false);
  else if (mode == 6 && bf32)             BGL(6, false, false, true, false);
  else                                    BGL2(7, true, true);
#undef BGL2
#undef BGL
}

// ---------------- fused flash attention ----------------
// Block = (q-tile, y in 0..11: z=y>>1 (b*2+h), half=y&1 of the 256 V cols).
// Q row s: qkv[(s*3+b)*1536 + h*256 + k]; K same +512; V^T: vt[z][256][mpad].
// S = (1/16) Q K^T; online softmax over m cols; O = P V; out token-major [T,512].
__global__ __launch_bounds__(256) void fattn_k(
    const bf16* __restrict__ qkv, const bf16* __restrict__ vt,
    bf16* __restrict__ out, int m, int mpad) {
  const int q0 = blockIdx.x * 128;
  const int zz = blockIdx.y;
  const int z = zz >> 1, half = zz & 1;
  const int b = z >> 1, h = z & 1;
  const bf16* Q = qkv + (long long)b * 1536 + h * 256;   // row stride 4608
  const bf16* Kp = Q + 512;
  const bf16* Vh = vt + ((long long)z * 256 + half * 128) * mpad;  // [128][mpad]

  __shared__ bf16 SAB[256 * 32];       // Q(128x32)+K(128x32) or V-slice(128x32)
  __shared__ bf16 Pl[128 * 136];       // P tile, padded pitch
  __shared__ float rred[2][128];
  __shared__ float mrow[128], lrow[128], newm[128], rs[128];

  const int tid = threadIdx.x;
  const int l = tid & 63;
  const int wr = ((tid >> 7) & 1) * 64;
  const int wc = ((tid >> 6) & 1) * 64;
  const int wcH = wc >> 6;

  f32x4 acc_o[4][4];
#pragma unroll
  for (int i = 0; i < 4; ++i)
#pragma unroll
    for (int j = 0; j < 4; ++j) acc_o[i][j] = (f32x4){0.f, 0.f, 0.f, 0.f};
  if (tid < 128) { mrow[tid] = -3.4e38f; lrow[tid] = 0.f; }
  __syncthreads();

  const int ntiles = (m + 127) / 128;
  for (int t = 0; t < ntiles; ++t) {
    const int kv0 = t * 128;
    // ---- S = Q K^T (single-stream GEMM over K-dim 256) ----
    f32x4 acc_s[4][4];
#pragma unroll
    for (int i = 0; i < 4; ++i)
#pragma unroll
      for (int j = 0; j < 4; ++j) acc_s[i][j] = (f32x4){0.f, 0.f, 0.f, 0.f};
    for (int k0 = 0; k0 < 256; k0 += 32) {
#pragma unroll
      for (int r = 0; r < 2; ++r) {
        int idx = r * 256 + tid;
        int row = idx >> 2, cs = idx & 3;
        int cg = cs ^ (row & 3);
        int qr = q0 + row; if (qr > m - 1) qr = m - 1;
        int kr = kv0 + row; if (kr > m - 1) kr = m - 1;
        gload_lds16(Q + (long long)qr * 4608 + k0 + cg * 8, &SAB[idx * 8]);
        gload_lds16(Kp + (long long)kr * 4608 + k0 + cg * 8, &SAB[4096 + idx * 8]);
      }
      __syncthreads();
      s16x8 af[4], bh4[4];
#pragma unroll
      for (int mi = 0; mi < 4; ++mi) {
        int row = wr + mi * 16 + (l & 15);
        int ch = ((l >> 4) ^ row) & 3;
        af[mi] = *reinterpret_cast<const s16x8*>(&SAB[row * 32 + ch * 8]);
      }
#pragma unroll
      for (int ni = 0; ni < 4; ++ni) {
        int row = wc + ni * 16 + (l & 15);
        int ch = ((l >> 4) ^ row) & 3;
        bh4[ni] = *reinterpret_cast<const s16x8*>(&SAB[4096 + row * 32 + ch * 8]);
      }
#pragma unroll
      for (int mi = 0; mi < 4; ++mi)
#pragma unroll
        for (int ni = 0; ni < 4; ++ni)
          acc_s[mi][ni] =
              __builtin_amdgcn_mfma_f32_16x16x32_bf16(af[mi], bh4[ni], acc_s[mi][ni], 0, 0, 0);
      __syncthreads();
    }
    // ---- row max of this tile ----
#pragma unroll
    for (int mi = 0; mi < 4; ++mi)
#pragma unroll
      for (int jj = 0; jj < 4; ++jj) {
        float v = -3.4e38f;
#pragma unroll
        for (int ni = 0; ni < 4; ++ni) v = fmaxf(v, acc_s[mi][ni][jj]);
        v *= 0.0625f;
        v = fmaxf(v, __shfl_xor(v, 1));
        v = fmaxf(v, __shfl_xor(v, 2));
        v = fmaxf(v, __shfl_xor(v, 4));
        v = fmaxf(v, __shfl_xor(v, 8));
        if ((l & 15) == 0) rred[wcH][wr + mi * 16 + (l >> 4) * 4 + jj] = v;
      }
    __syncthreads();
    if (tid < 128) {
      float tm = fmaxf(rred[0][tid], rred[1][tid]);
      float mo = mrow[tid];
      float mn = fmaxf(mo, tm);
      newm[tid] = mn;
      float r = expf(mo - mn);   // first tile: exp(-inf)=0
      rs[tid] = r;
      mrow[tid] = mn;
      lrow[tid] *= r;
    }
    __syncthreads();
    // ---- P = exp(S - m), write to LDS, rowsum; rescale O ----
#pragma unroll
    for (int mi = 0; mi < 4; ++mi)
#pragma unroll
      for (int jj = 0; jj < 4; ++jj) {
        int row = wr + mi * 16 + (l >> 4) * 4 + jj;
        float mn = newm[row];
        float r = rs[row];
        float s = 0.f;
#pragma unroll
        for (int ni = 0; ni < 4; ++ni) {
          int col = wc + ni * 16 + (l & 15);
          float p = (kv0 + col < m) ? expf(acc_s[mi][ni][jj] * 0.0625f - mn) : 0.f;
          Pl[row * 136 + col] = (bf16)p;
          s += p;
          acc_o[mi][ni][jj] *= r;
        }
        s += __shfl_xor(s, 1);
        s += __shfl_xor(s, 2);
        s += __shfl_xor(s, 4);
        s += __shfl_xor(s, 8);
        if ((l & 15) == 0) rred[wcH][row] = s;
      }
    __syncthreads();
    if (tid < 128) lrow[tid] += rred[0][tid] + rred[1][tid];
    // ---- O += P V ----
    int klim = m - kv0; if (klim > 128) klim = 128;
    for (int k0 = 0; k0 < klim; k0 += 32) {
#pragma unroll
      for (int r = 0; r < 2; ++r) {
        int idx = r * 256 + tid;
        int row = idx >> 2, cs = idx & 3;
        int cg = cs ^ (row & 3);
        int col = kv0 + k0 + cg * 8;
        if (col > mpad - 8) col = mpad - 8;
        gload_lds16(Vh + (long long)row * mpad + col, &SAB[idx * 8]);
      }
      __syncthreads();
      s16x8 pf[4], vf[4];
#pragma unroll
      for (int mi = 0; mi < 4; ++mi) {
        int pr = wr + mi * 16 + (l & 15);
        pf[mi] = *reinterpret_cast<const s16x8*>(&Pl[pr * 136 + k0 + (l >> 4) * 8]);
      }
#pragma unroll
      for (int ni = 0; ni < 4; ++ni) {
        int vr = wc + ni * 16 + (l & 15);
        int ch = ((l >> 4) ^ vr) & 3;
        vf[ni] = *reinterpret_cast<const s16x8*>(&SAB[vr * 32 + ch * 8]);
      }
#pragma unroll
      for (int mi = 0; mi < 4; ++mi)
#pragma unroll
        for (int ni = 0; ni < 4; ++ni)
          acc_o[mi][ni] =
              __builtin_amdgcn_mfma_f32_16x16x32_bf16(pf[mi], vf[ni], acc_o[mi][ni], 0, 0, 0);
      __syncthreads();
    }
  }
  __syncthreads();
  // ---- normalize + store ----
#pragma unroll
  for (int mi = 0; mi < 4; ++mi)
#pragma unroll
    for (int jj = 0; jj < 4; ++jj) {
      int row = wr + mi * 16 + (l >> 4) * 4 + jj;
      int gr = q0 + row;
      if (gr >= m) continue;
      float linv = 1.f / lrow[row];
#pragma unroll
      for (int ni = 0; ni < 4; ++ni) {
        int n = half * 128 + wc + ni * 16 + (l & 15);
        out[(long long)gr * 1536 + b * 512 + h * 256 + n] = (bf16)(acc_o[mi][ni][jj] * linv);
      }
    }
}

// ---------------- fp32 -> (hi, lo) bf16 split, segmented; ptrs computed on host ------
struct SegArgs {
  const float* src[8];
  bf16* hi[8];
  bf16* lo[8];
  int start[9];
};
__global__ __launch_bounds__(256) void split_k(SegArgs a, int total8) {
  for (int i = blockIdx.x * 256 + threadIdx.x; i < total8; i += gridDim.x * 256) {
    int s = 0;
    while (i >= a.start[s + 1]) ++s;
    long long off = (long long)(i - a.start[s]) * 8;
    const float4* p = reinterpret_cast<const float4*>(a.src[s] + off);
    float4 x = p[0], y = p[1];
    float w[8] = {x.x, x.y, x.z, x.w, y.x, y.y, y.z, y.w};
    bf16 hb[8], lb[8];
#pragma unroll
    for (int q = 0; q < 8; ++q) {
      bf16 hq = (bf16)w[q];
      hb[q] = hq;
      lb[q] = (bf16)(w[q] - (float)hq);
    }
    *reinterpret_cast<s16x8*>(a.hi[s] + off) = *reinterpret_cast<s16x8*>(hb);
    if (a.lo[s]) *reinterpret_cast<s16x8*>(a.lo[s] + off) = *reinterpret_cast<s16x8*>(lb);
  }
}

// ---------------- embedding gather + concat + time-pos + mask -> bf16 ----------------
__global__ __launch_bounds__(256) void embed_k(
    const int* __restrict__ uid, const int* __restrict__ pid, const int* __restrict__ cid,
    const int* __restrict__ gid, const int* __restrict__ tmid, const int* __restrict__ mask,
    const float* __restrict__ ue, const float* __restrict__ pe, const float* __restrict__ ce,
    const float* __restrict__ ge, const float* __restrict__ tp, bf16* __restrict__ xb) {
  int e = blockIdx.x * 256 + threadIdx.x;
  if (e >= NN * ED) return;
  int n = e / ED, j = e - n * ED;
  int mi = mask[n];
  float fm = (float)mi;
  float v;
  if (j < 128)      v = ue[(long long)(uid[n] * mi) * 128 + j];
  else if (j < 256) v = pe[(long long)(pid[n] * mi) * 128 + (j - 128)];
  else if (j < 288) v = ce[(long long)(cid[n] * mi) * 32 + (j - 256)];
  else              v = ge[(long long)(gid[n] * mi) * 64 + (j - 288)];
  v += 0.5f * tp[(long long)(tmid[n] * mi) * ED + j];
  xb[e] = (bf16)(v * fm);
}

// ---------------- forget gates + c_red ----------------
__global__ __launch_bounds__(256) void fcred_k(
    const float* __restrict__ wxa, const float* __restrict__ ufh,
    const float* __restrict__ bf_, const float* __restrict__ c, float* __restrict__ cred,
    int m, int cbase, int tl, int woff) {
  int e = blockIdx.x * 256 + threadIdx.x;
  if (e >= m * 512) return;
  int r = e >> 9, d = e & 511;
  float w = wxa[(long long)(woff + r) * 512 + d] + bf_[d];
  int t = r / tl, p = r - t * tl;
  long long cb = (long long)(cbase + t * 3 * tl + 3 * p) * 512 + d;
  long long ub = (long long)r * 1536;
  float acc = 0.f;
#pragma unroll
  for (int k = 0; k < 3; ++k) {
    float f = sigmoidf_(w + ufh[ub + k * 512 + d]);
    acc += f * c[cb + (long long)k * 512];
  }
  cred[e] = acc;
}

// ---------------- iou -> (h,c); h pair + scatter into next level's mailbox ----------
__global__ __launch_bounds__(256) void combine_k(
    const float* __restrict__ iou, const float* __restrict__ cred, float* __restrict__ c,
    bf16* __restrict__ hhi, bf16* __restrict__ hlo, int off, int m, int tl3, int tlp,
    bf16* __restrict__ nxthi, bf16* __restrict__ nxtlo) {
  int e = blockIdx.x * 256 + threadIdx.x;
  if (e >= m * 512) return;
  int r = e >> 9, d = e & 511;
  long long b = (long long)r * 1536;
  float iv = iou[b + d], ov = iou[b + 512 + d], uv = iou[b + 1024 + d];
  float cr = cred ? cred[e] : 0.f;
  float cn = sigmoidf_(iv) * tanhf(uv) + cr;
  float hn = sigmoidf_(ov) * tanhf(cn);
  long long o = (long long)(off + r) * 512 + d;
  c[o] = cn;
  bf16 hv = (bf16)hn;
  bf16 lo = (bf16)(hn - (float)hv);
  hhi[o] = hv;
  hlo[o] = lo;
  if (nxthi) {
    int t = r / tl3, q = r - t * tl3;
    int qp = q / 3, slot = q - 3 * qp;
    long long dst = (long long)(t * tlp + qp) * 1536 + slot * 512 + d;
    nxthi[dst] = hv;
    nxtlo[dst] = lo;
  }
}

// ---------------- LayerNorm width 512: LN((ahi+alo) + b)*w + bias -> pair ----------
__global__ __launch_bounds__(256) void ln_k(
    const bf16* __restrict__ ahi, const bf16* __restrict__ alo, const float* __restrict__ b,
    const float* __restrict__ w, const float* __restrict__ bias,
    bf16* __restrict__ ohi, bf16* __restrict__ olo) {
  int r = blockIdx.x, t = threadIdx.x;
  long long base = (long long)r * 512;
  float v0 = (float)ahi[base + t] + (float)alo[base + t] + b[base + t];
  float v1 = (float)ahi[base + 256 + t] + (float)alo[base + 256 + t] + b[base + 256 + t];
  __shared__ float s1[256], s2[256];
  s1[t] = v0 + v1;
  s2[t] = v0 * v0 + v1 * v1;
  __syncthreads();
  for (int s = 128; s > 0; s >>= 1) {
    if (t < s) { s1[t] += s1[t + s]; s2[t] += s2[t + s]; }
    __syncthreads();
  }
  float mu = s1[0] * (1.f / 512.f);
  float var = s2[0] * (1.f / 512.f) - mu * mu;
  float rs = rsqrtf(var + 1e-5f);
  float o0 = (v0 - mu) * rs * w[t] + bias[t];
  float o1 = (v1 - mu) * rs * w[256 + t] + bias[256 + t];
  bf16 h0 = (bf16)o0, h1 = (bf16)o1;
  ohi[base + t] = h0;       olo[base + t] = (bf16)(o0 - (float)h0);
  ohi[base + 256 + t] = h1; olo[base + 256 + t] = (bf16)(o1 - (float)h1);
}

}  // namespace

extern "C" void kernel_launch(void* const* d_in, const int* in_sizes, int n_in,
                              void* d_out, int out_size, void* d_ws, size_t ws_size,
                              hipStream_t stream) {
  const int* uid  = (const int*)d_in[0];
  const int* pid  = (const int*)d_in[1];
  const int* cid  = (const int*)d_in[2];
  const int* gid  = (const int*)d_in[3];
  const int* tmid = (const int*)d_in[4];
  const int* mask = (const int*)d_in[5];
  const float* ue = (const float*)d_in[6];
  const float* pe = (const float*)d_in[7];
  const float* ce = (const float*)d_in[8];
  const float* ge = (const float*)d_in[9];
  const float* tp = (const float*)d_in[10];
  const float* b_iou = (const float*)d_in[13];
  const float* b_f = (const float*)d_in[16];
  const float* qkv_b = (const float*)d_in[18];
  const float* out_b = (const float*)d_in[20];
  const float* ln1_w = (const float*)d_in[21];
  const float* ln1_b = (const float*)d_in[22];
  const float* ff1_b = (const float*)d_in[24];
  const float* ff2_b = (const float*)d_in[26];
  const float* ln2_w = (const float*)d_in[27];
  const float* ln2_b = (const float*)d_in[28];
  const float* dpw = (const float*)d_in[29];
  const float* dpb = (const float*)d_in[30];
  const float* dcw = (const float*)d_in[31];
  const float* dcb = (const float*)d_in[32];
  const float* dgw = (const float*)d_in[33];
  const float* dgb = (const float*)d_in[34];

  // ---- d_ws ----
  float* ws = (float*)d_ws;
  bf16* Hhi = (bf16*)ws;
  bf16* Hlo = Hhi + 2981888LL;
  float* Cc = ws + 2981888LL;
  bf16* DhiW = (bf16*)(ws + 5963776LL);
  const bool wsfit = ws_size >= 30330880ULL;

  // ---- d_out map (fl offsets) ----
  float* ob = (float*)d_out;
  float* IOUa = ob;                            // [0, 8,945,664)
  float* WXa  = ob + 8945664LL;
  float* CRED = ob + 9936896LL;
  bf16* RAhi  = (bf16*)(ob + 10600448LL);
  bf16* RAlo  = RAhi + 1990656LL;
  bf16* RBhi  = (bf16*)(ob + 12591104LL);
  bf16* RBlo  = RBhi + 1990656LL;
  bf16* UP    = (bf16*)(ob + 14581760LL);
  bf16* TE    = (bf16*)(ob + 19300352LL);
  float* TB   = ob + 22446080LL;               // transient, 14,384,896 fl

  bf16* Uihi = UP;
  bf16* Uilo = UP + 2359296LL;
  bf16* Ufhi = UP + 4718592LL;
  bf16* Uflo = UP + 7077888LL;
  bf16* qkvhi = TE;
  bf16* qkvlo = TE + 1572864LL;
  bf16* outhi = TE + 3145728LL;
  bf16* outlo = TE + 3670016LL;
  bf16* ff1hi = TE + 4194304LL;
  bf16* ff1lo = TE + 4718592LL;
  bf16* ff2hi = TE + 5242880LL;
  bf16* ff2lo = TE + 5767168LL;

  // TB layout during level loop:
  bf16* ATTOb = (bf16*)TB;                     // [T,512] bf16 = 995,328 fl
  float* XB   = TB + 995328LL;                 // fp32 [T,512]
  bf16* XChi  = (bf16*)(TB + 1990656LL);
  bf16* XClo  = (bf16*)(TB + 2985984LL);
  float* PQ   = TB + 10077696LL;               // UFH / QKVb
  bf16* VT    = (bf16*)(TB + 13063680LL);      // 2,015,232 el
  // early-phase aliases in TB (dead before transformer):
  bf16* Xb    = (bf16*)TB;
  bf16* WP    = (bf16*)(TB + 1025024LL);
  bf16* Wihi  = WP;
  bf16* Wilo  = WP + 540672LL;
  bf16* Wfhi  = WP + 1081344LL;
  bf16* Wflo  = WP + 1261568LL;

  float* UFH  = PQ;
  bf16* QKVb  = (bf16*)PQ;

  // 0) weight splits
  {
    SegArgs a{};
    const int n8[8] = {294912, 294912, 196608, 65536, 65536, 65536, 67584, 22528};
    a.src[0] = (const float*)d_in[12]; a.hi[0] = Uihi;  a.lo[0] = Uilo;
    a.src[1] = (const float*)d_in[15]; a.hi[1] = Ufhi;  a.lo[1] = Uflo;
    a.src[2] = (const float*)d_in[17]; a.hi[2] = qkvhi; a.lo[2] = qkvlo;
    a.src[3] = (const float*)d_in[19]; a.hi[3] = outhi; a.lo[3] = outlo;
    a.src[4] = (const float*)d_in[23]; a.hi[4] = ff1hi; a.lo[4] = ff1lo;
    a.src[5] = (const float*)d_in[25]; a.hi[5] = ff2hi; a.lo[5] = ff2lo;
    a.src[6] = (const float*)d_in[11]; a.hi[6] = Wihi;  a.lo[6] = Wilo;
    a.src[7] = (const float*)d_in[14]; a.hi[7] = Wfhi;  a.lo[7] = Wflo;
    a.start[0] = 0;
    for (int i = 0; i < 8; ++i) a.start[i + 1] = a.start[i] + n8[i];
    int total8 = a.start[8];
    int blocks = (total8 + 255) / 256; if (blocks > 4096) blocks = 4096;
    split_k<<<blocks, 256, 0, stream>>>(a, total8);
    if (wsfit) {
      SegArgs d{};
      const int dn8[3] = {320000, 19200, 65536};
      d.src[0] = dpw; d.hi[0] = DhiW;             d.lo[0] = nullptr;
      d.src[1] = dcw; d.hi[1] = DhiW + 2560000LL; d.lo[1] = nullptr;
      d.src[2] = dgw; d.hi[2] = DhiW + 2713600LL; d.lo[2] = nullptr;
      d.start[0] = 0;
      for (int i = 0; i < 3; ++i) d.start[i + 1] = d.start[i] + dn8[i];
      for (int i = 3; i < 8; ++i) d.start[i + 1] = d.start[3];
      int dt8 = d.start[3];
      int db = (dt8 + 255) / 256; if (db > 4096) db = 4096;
      split_k<<<db, 256, 0, stream>>>(d, dt8);
    }
  }

  // 1) embeddings
  embed_k<<<(NN * ED + 255) / 256, 256, 0, stream>>>(uid, pid, cid, gid, tmid, mask,
                                                     ue, pe, ce, ge, tp, Xb);

  // 2) hoisted projections
  bgemm(stream, 0, false, true, Xb, nullptr, Wihi, Wilo, IOUa, nullptr, nullptr,
        nullptr, nullptr, nullptr, nullptr, 0, NN, 1536, 352, 352, 352, 1536, 1.f);
  bgemm(stream, 0, false, true, Xb + 3888LL * ED, nullptr, Wfhi, Wflo, WXa, nullptr,
        nullptr, nullptr, nullptr, nullptr, nullptr, 0, 1936, 512, 352, 352, 352, 512, 1.f);

  // 3) leaves
  combine_k<<<(3888 * 512 + 255) / 256, 256, 0, stream>>>(
      IOUa, nullptr, Cc, Hhi, Hlo, 0, 3888, 243, 81, RAhi, RAlo);

  static const int OFFL[6] = {5808, 5760, 5616, 5184, 3888, 0};
  int tl = 81;
  for (int l = 4; l >= 0; --l, tl /= 3) {
    int m = 16 * tl;
    int off = OFFL[l];
    int cbase = OFFL[l + 1];
    int T = 3 * m;
    int mpad = (m + 31) & ~31;

    bgemm(stream, 0, true, true, RAhi, RAlo, Ufhi, Uflo, UFH, nullptr, nullptr,
          nullptr, nullptr, nullptr, nullptr, 0, m, 1536, 1536, 1536, 1536, 1536, 1.f);
    fcred_k<<<(m * 512 + 255) / 256, 256, 0, stream>>>(WXa, UFH, b_f, Cc, CRED,
                                                       m, cbase, tl, off - 3888);

    bf16 *curhi = RAhi, *curlo = RAlo, *nxthi = RBhi, *nxtlo = RBlo;
    for (int i = 0; i < 2; ++i) {
      bgemm(stream, 7, true, true, curhi, curlo, qkvhi + (long long)i * 786432,
            qkvlo + (long long)i * 786432, QKVb, nullptr, nullptr,
            qkv_b + i * 1536, nullptr, nullptr, VT, mpad,
            T, 1536, 512, 512, 512, 1536, 1.f);
      // fused attention: scores + softmax + PV
      {
        int ntiles = (m + 127) / 128;
        fattn_k<<<dim3(ntiles, 12), 256, 0, stream>>>(QKVb, VT, ATTOb, m, mpad);
      }
      bgemm(stream, 0, false, true, ATTOb, nullptr, outhi + (long long)i * 262144,
            outlo + (long long)i * 262144, XB, nullptr, nullptr,
            out_b + i * 512, nullptr, nullptr, nullptr, 0,
            T, 512, 512, 512, 512, 512, 1.f);
      ln_k<<<T, 256, 0, stream>>>(curhi, curlo, XB, ln1_w + i * 512, ln1_b + i * 512,
                                  nxthi, nxtlo);
      bgemm(stream, 4, true, true, nxthi, nxtlo, ff1hi + (long long)i * 262144,
            ff1lo + (long long)i * 262144, XChi, XClo, nullptr,
            ff1_b + i * 512, nullptr, nullptr, nullptr, 0,
            T, 512, 512, 512, 512, 512, 1.f);
      bgemm(stream, 0, true, true, XChi, XClo, ff2hi + (long long)i * 262144,
            ff2lo + (long long)i * 262144, XB, nullptr, nullptr,
            ff2_b + i * 512, nullptr, nullptr, nullptr, 0,
            T, 512, 512, 512, 512, 512, 1.f);
      ln_k<<<T, 256, 0, stream>>>(nxthi, nxtlo, XB, ln2_w + i * 512, ln2_b + i * 512,
                                  curhi, curlo);
    }

    bgemm(stream, 5, true, true, curhi, curlo, Uihi, Uilo,
          IOUa + (long long)off * 1536, nullptr, IOUa + (long long)off * 1536,
          b_iou, nullptr, nullptr, nullptr, 0, m, 1536, 1536, 1536, 1536, 1536, 1.f);
    combine_k<<<(m * 512 + 255) / 256, 256, 0, stream>>>(
        IOUa + (long long)off * 1536, CRED, Cc, Hhi, Hlo, off, m, tl, tl / 3,
        l > 0 ? RAhi : nullptr, l > 0 ? RAlo : nullptr);
  }

  // 4) merged decoders (weights strictly outside d_out)
  if (wsfit) {
    bgemm(stream, 6, false, false, Hhi, nullptr, DhiW, nullptr, ob, nullptr, nullptr,
          dpb, dcb, dgb, nullptr, 0, NN, 6324, 512, 512, 512, 0, 1.f);
  } else {
    bgemm(stream, 6, false, false, Hhi, nullptr, nullptr, nullptr, ob, nullptr, nullptr,
          dpb, dcb, dgb, nullptr, 0, NN, 6324, 512, 512, 512, 0, 1.f,
          1, 0, 0, 0, 0, 0, 0, 1, dpw, dcw, dgw, true);
  }
}